// Round 4
// baseline (360.596 us; speedup 1.0000x reference)
//
#include <hip/hip_runtime.h>

constexpr int N_TOKENS = 16384;
constexpr int D_MODEL  = 2048;

// One WAVE per token row (4 rows per 256-thread block).
// Lane t, chunk k handles elements 256k + 4t .. +4  (perfectly coalesced
// 1 KiB/wave float4 transactions). x row lives in 32 VGPRs between the
// gate dot-product and the output scaling, so x is read from HBM once.
// Butterfly __shfl_xor reduction leaves the full dot in ALL lanes ->
// no LDS, no __syncthreads, no divergent serial section.
__global__ __launch_bounds__(256) void wbr_kernel(
    const float* __restrict__ x,
    const float* __restrict__ gw,   // (D_MODEL, 2) interleaved: gw[2*d + branch]
    const float* __restrict__ gb,   // (2,)
    float* __restrict__ out)        // pre_x then post_x, each N_TOKENS*D_MODEL
{
    const int lane = threadIdx.x & 63;
    const int row  = (blockIdx.x << 2) | (threadIdx.x >> 6);
    const size_t rbase = (size_t)row * D_MODEL;
    const float* xr = x + rbase;

    float4 xv[8];
    double d0 = 0.0, d1 = 0.0;
    #pragma unroll
    for (int k = 0; k < 8; ++k) {
        const int e = (k << 8) + (lane << 2);
        xv[k] = *reinterpret_cast<const float4*>(xr + e);
        // gate_w for d = e..e+3 (branch0/branch1 interleaved), L1/L2-resident
        const float4 w0 = *reinterpret_cast<const float4*>(gw + 2 * e);
        const float4 w1 = *reinterpret_cast<const float4*>(gw + 2 * e + 4);
        // f64 accumulation: exact sign for the mask decision (threshold z==0)
        d0 += (double)xv[k].x * w0.x + (double)xv[k].y * w0.z
            + (double)xv[k].z * w1.x + (double)xv[k].w * w1.z;
        d1 += (double)xv[k].x * w0.y + (double)xv[k].y * w0.w
            + (double)xv[k].z * w1.y + (double)xv[k].w * w1.w;
    }

    // wave64 butterfly: full sum lands in every lane
    #pragma unroll
    for (int off = 1; off < 64; off <<= 1) {
        d0 += __shfl_xor(d0, off);
        d1 += __shfl_xor(d1, off);
    }

    const double z0 = d0 + (double)gb[0];
    const double z1 = d1 + (double)gb[1];
    const int m0 = z0 > 0.0;
    const int m1 = z1 > 0.0;
    // sign decided in f64; magnitude in f32 is plenty (tol 0.32, |ds|~1e-6)
    const float s0 = m0 ? 1.0f / (1.0f + __expf(-(float)z0)) : 0.0f;
    const float s1 = m1 ? 1.0f / (1.0f + __expf(-(float)z1)) : 0.0f;
    const float a = s0 + s1;                  // pre_x scale
    const float b = (float)(m0 + m1) * a;     // post_x scale

    float* pre  = out + rbase;
    float* post = out + (size_t)N_TOKENS * D_MODEL + rbase;
    #pragma unroll
    for (int k = 0; k < 8; ++k) {
        const int e = (k << 8) + (lane << 2);
        *reinterpret_cast<float4*>(pre + e)  =
            make_float4(xv[k].x * a, xv[k].y * a, xv[k].z * a, xv[k].w * a);
        *reinterpret_cast<float4*>(post + e) =
            make_float4(xv[k].x * b, xv[k].y * b, xv[k].z * b, xv[k].w * b);
    }
}

extern "C" void kernel_launch(void* const* d_in, const int* in_sizes, int n_in,
                              void* d_out, int out_size, void* d_ws, size_t ws_size,
                              hipStream_t stream) {
    const float* x  = (const float*)d_in[0];
    const float* gw = (const float*)d_in[1];
    const float* gb = (const float*)d_in[2];
    float* out = (float*)d_out;
    wbr_kernel<<<N_TOKENS / 4, 256, 0, stream>>>(x, gw, gb, out);
}